// Round 11
// baseline (121.562 us; speedup 1.0000x reference)
//
#include <hip/hip_runtime.h>
#include <hip/hip_bf16.h>

typedef __bf16 bf16_t;
typedef __attribute__((ext_vector_type(4))) float f32x4;
typedef __attribute__((ext_vector_type(8))) __bf16 bf16x8;
typedef __attribute__((ext_vector_type(4))) __bf16 bf16x4;
typedef __attribute__((ext_vector_type(2))) __bf16 bf16x2;

#define NQ    1024
#define DIM   384
#define NHEAD 8
#define HDIM  48
#define HALFD 24
#define NKEY  196
#define TOTAL 5440   // 64*64 + 32*32 + 16*16 + 8*8

typedef __attribute__((address_space(1))) void gas_void;
typedef __attribute__((address_space(3))) void las_void;
__device__ __forceinline__ void gload16(const void* g, void* l) {
    __builtin_amdgcn_global_load_lds((gas_void*)g, (las_void*)l, 16, 0, 0);
}

// ---------------------------------------------------------------------------
// prep: weights fp32->bf16 (blocks 0..575), sincos tables (block 576).
// ---------------------------------------------------------------------------
__global__ __launch_bounds__(256) void prep_kernel(
    const float* __restrict__ wq, const float* __restrict__ wkv,
    const float* __restrict__ wout, bf16_t* __restrict__ wq_bf,
    bf16_t* __restrict__ wkv_bf, bf16_t* __restrict__ wout_bf,
    float2* __restrict__ tabS, float2* __restrict__ tabL)
{
    int bid = blockIdx.x;
    if (bid == 576) {
        int t = threadIdx.x;
        if (t < 512) {
            int i = t >> 3, f = t & 7;
            float fr = powf(10.f, -(float)f / 8.f);
            float s, c; sincosf((float)i * fr, &s, &c);
            tabS[t] = make_float2(c, s);
        } else if (t < 544) {
            int u = t - 512; int l = u >> 3, f = u & 7;
            float fr = powf(10.f, (float)f / 8.f);
            float s, c; sincosf((float)l * fr, &s, &c);
            tabL[u] = make_float2(c, s);
        }
        return;
    }
    int i = bid * 256 + threadIdx.x;
    const float* src; bf16_t* dst; int off;
    if (i < 36864)       { src = wq;   dst = wq_bf;   off = i; }
    else if (i < 110592) { src = wkv;  dst = wkv_bf;  off = i - 36864; }
    else                 { src = wout; dst = wout_bf; off = i - 110592; }
    float4 v = ((const float4*)src)[off];
    bf16x4 o = { (bf16_t)v.x, (bf16_t)v.y, (bf16_t)v.z, (bf16_t)v.w };
    ((bf16x4*)dst)[off] = o;
}

// ---------------------------------------------------------------------------
// bf16 NT GEMM: C[M,N] = A[M,K] * B[N,K]^T, MFMA 16x16x32, BK=64.
// AF32=1: A is fp32 in global; staged fp32 via global_load_lds with 32B-block
// XOR swizzle, converted to bf16 in registers at fragment build.
// EPI: 0 = fp32 C, 1 = fp32 C + resid, 2 = bf16 C.  BT = 128 or 64.
// ---------------------------------------------------------------------------
template<int EPI, int BT, int AF32>
__global__ __launch_bounds__(256) void gemm_bf16(
    const void* __restrict__ Ap, const bf16_t* __restrict__ Bw,
    void* __restrict__ Cp, const float* __restrict__ resid,
    int M, int Nout, int K)
{
    constexpr int FRG = BT / 32;
    constexpr int WT  = BT / 2;
    __shared__ bf16_t As[AF32 ? 1 : BT * 64];
    __shared__ float  As32[AF32 ? BT * 64 : 1];
    __shared__ bf16_t Bs[BT * 64];
    const int tid = threadIdx.x;

    const int bid = blockIdx.y * gridDim.x + blockIdx.x;
    const int nwg = gridDim.x * gridDim.y;
    const int qq = nwg >> 3, rr8 = nwg & 7;
    const int xcd = bid & 7, loc = bid >> 3;
    const int swz = (xcd < rr8 ? xcd * (qq + 1) : rr8 * (qq + 1) + (xcd - rr8) * qq) + loc;
    const int bm = swz / gridDim.x, bn = swz % gridDim.x;

    const int wave = tid >> 6, lane = tid & 63;
    const int wr   = wave >> 1, wc = wave & 1;
    const int fr   = lane & 15, g = lane >> 4;

    f32x4 acc[FRG][FRG];
#pragma unroll
    for (int i = 0; i < FRG; ++i)
#pragma unroll
        for (int j = 0; j < FRG; ++j) acc[i][j] = (f32x4){0.f, 0.f, 0.f, 0.f};

    const bf16_t* Ab  = (const bf16_t*)Ap + (size_t)bm * BT * K;
    const float*  Abf = (const float*) Ap + (size_t)bm * BT * K;
    const bf16_t* Bb  = Bw + (size_t)bn * BT * K;

    for (int kt = 0; kt < K; kt += 64) {
        __syncthreads();
        if (AF32) {
            // A fp32: BT x 64 floats; physical 32B-block pb holds logical
            // block pb ^ (row & 7)  (XOR involution; read applies same XOR)
#pragma unroll
            for (int it = 0; it < BT / 16; ++it) {
                int chunk = it * 256 + tid;           // 16B chunk
                int row = chunk >> 4, c16 = chunk & 15;
                int blk = c16 >> 1, half = c16 & 1;
                int sblk = blk ^ (row & 7);
                gload16(Abf + (size_t)row * K + kt + sblk * 8 + half * 4,
                        As32 + chunk * 4);
            }
#pragma unroll
            for (int it = 0; it < BT / 32; ++it) {
                int chunk = it * 256 + tid;
                int row = chunk >> 3, c8 = chunk & 7;
                int sc8 = c8 ^ (row & 7);
                gload16(Bb + (size_t)row * K + kt + sc8 * 8, Bs + chunk * 8);
            }
        } else {
#pragma unroll
            for (int it = 0; it < BT / 32; ++it) {
                int chunk = it * 256 + tid;
                int row = chunk >> 3, c8 = chunk & 7;
                int sc8 = c8 ^ (row & 7);
                gload16(Ab + (size_t)row * K + kt + sc8 * 8, As + chunk * 8);
                gload16(Bb + (size_t)row * K + kt + sc8 * 8, Bs + chunk * 8);
            }
        }
        __syncthreads();
#pragma unroll
        for (int kk = 0; kk < 2; ++kk) {
            bf16x8 af[FRG], bfr[FRG];
#pragma unroll
            for (int mi = 0; mi < FRG; ++mi) {
                int row = wr * WT + mi * 16 + fr;
                if (AF32) {
                    int blk = (kk * 4 + g) ^ (row & 7);
                    const float* p = As32 + row * 64 + blk * 8;
                    float4 lo = *(const float4*)p;
                    float4 hi = *(const float4*)(p + 4);
                    af[mi] = (bf16x8){ (bf16_t)lo.x, (bf16_t)lo.y, (bf16_t)lo.z, (bf16_t)lo.w,
                                       (bf16_t)hi.x, (bf16_t)hi.y, (bf16_t)hi.z, (bf16_t)hi.w };
                } else {
                    int c = (kk * 4 + g) ^ (row & 7);
                    af[mi] = *(const bf16x8*)(As + row * 64 + c * 8);
                }
            }
#pragma unroll
            for (int ni = 0; ni < FRG; ++ni) {
                int row = wc * WT + ni * 16 + fr;
                int c = (kk * 4 + g) ^ (row & 7);
                bfr[ni] = *(const bf16x8*)(Bs + row * 64 + c * 8);
            }
#pragma unroll
            for (int mi = 0; mi < FRG; ++mi)
#pragma unroll
                for (int ni = 0; ni < FRG; ++ni)
                    acc[mi][ni] = __builtin_amdgcn_mfma_f32_16x16x32_bf16(
                        af[mi], bfr[ni], acc[mi][ni], 0, 0, 0);
        }
    }

    const int r0 = g << 2;
#pragma unroll
    for (int mi = 0; mi < FRG; ++mi) {
#pragma unroll
        for (int ni = 0; ni < FRG; ++ni) {
#pragma unroll
            for (int e = 0; e < 4; ++e) {
                int row = bm * BT + wr * WT + mi * 16 + r0 + e;
                int col = bn * BT + wc * WT + ni * 16 + fr;
                float v = acc[mi][ni][e];
                if (EPI == 2) {
                    ((bf16_t*)Cp)[(size_t)row * Nout + col] = (bf16_t)v;
                } else {
                    if (EPI == 1) v += resid[(size_t)row * Nout + col];
                    ((float*)Cp)[(size_t)row * Nout + col] = v;
                }
            }
        }
    }
}

// ---------------------------------------------------------------------------
__global__ __launch_bounds__(64) void ln_kernel(
    const float* __restrict__ q, const float* __restrict__ w,
    const float* __restrict__ b, bf16_t* __restrict__ xout)
{
    const int n = blockIdx.x, lane = threadIdx.x;
    const float* row = q + (size_t)n * DIM;
    float v[6], s = 0.f, s2 = 0.f;
#pragma unroll
    for (int i = 0; i < 6; ++i) {
        v[i] = row[lane + i * 64];
        s += v[i]; s2 += v[i] * v[i];
    }
#pragma unroll
    for (int m = 32; m; m >>= 1) { s += __shfl_xor(s, m); s2 += __shfl_xor(s2, m); }
    float mu  = s * (1.f / DIM);
    float var = s2 * (1.f / DIM) - mu * mu;
    float rs  = rsqrtf(var + 1e-5f);
#pragma unroll
    for (int i = 0; i < 6; ++i) {
        int d = lane + i * 64;
        xout[(size_t)n * DIM + d] = (bf16_t)((v[i] - mu) * rs * w[d] + b[d]);
    }
}

// ---------------------------------------------------------------------------
// Pre-rotate the k-half of the kv map in place. One thread per (row, head).
// ---------------------------------------------------------------------------
__global__ __launch_bounds__(256) void rope_k_kernel(
    bf16_t* __restrict__ kvm, const float2* __restrict__ tabS,
    const float2* __restrict__ tabL, int Mkv)
{
    int t = blockIdx.x * 256 + threadIdx.x;
    if (t >= Mkv * NHEAD) return;
    int row = t >> 3, h = t & 7;

    int rr = row % TOTAL;
    int l, i, j;
    if (rr < 4096)      { l = 0; i = rr >> 6;               j = rr & 63; }
    else if (rr < 5120) { l = 1; int u = rr - 4096; i = u >> 5; j = u & 31; }
    else if (rr < 5376) { l = 2; int u = rr - 5120; i = u >> 4; j = u & 15; }
    else                { l = 3; int u = rr - 5376; i = u >> 3; j = u & 7;  }

    bf16_t* base = kvm + (size_t)row * (2 * DIM) + h * HDIM;
    bf16x8 xa[3], xb[3];
#pragma unroll
    for (int k = 0; k < 3; ++k) {
        xa[k] = *(const bf16x8*)(base + 8 * k);
        xb[k] = *(const bf16x8*)(base + HALFD + 8 * k);
    }
#pragma unroll
    for (int d = 0; d < HALFD; ++d) {
        float2 cs = (d < 8) ? tabS[i * 8 + d]
                  : (d < 16) ? tabS[j * 8 + (d - 8)]
                             : tabL[l * 8 + (d - 16)];
        float x1 = (float)xa[d >> 3][d & 7];
        float x2 = (float)xb[d >> 3][d & 7];
        xa[d >> 3][d & 7] = (bf16_t)(x1 * cs.x - x2 * cs.y);
        xb[d >> 3][d & 7] = (bf16_t)(x1 * cs.y + x2 * cs.x);
    }
#pragma unroll
    for (int k = 0; k < 3; ++k) {
        *(bf16x8*)(base + 8 * k)         = xa[k];
        *(bf16x8*)(base + HALFD + 8 * k) = xb[k];
    }
}

// ---------------------------------------------------------------------------
// Attention: one block (256 threads) per query — R7-proven structure.
// XCD-chunked query remap: XCD x serves queries [128x, 128x+128).
// ---------------------------------------------------------------------------
__global__ __launch_bounds__(256) void attn_kernel(
    const float* __restrict__ qproj,   // (N,384) pre-RoPE fp32
    const int*   __restrict__ pos,     // (N,4) b,i,j,l
    const bf16_t* __restrict__ kvm,    // (B*total, 768) bf16, k pre-rotated
    const float2* __restrict__ tabS, const float2* __restrict__ tabL,
    bf16_t* __restrict__ attn_out)     // (N,384) bf16
{
    __shared__ float qs[DIM];
    __shared__ float sc[NHEAD * NKEY];
    __shared__ int   flatL[NKEY], validL[NKEY];

    const int bid = blockIdx.x, tid = threadIdx.x;
    const int n = ((bid & 7) << 7) | (bid >> 3);   // XCD-chunked remap
    const int b  = pos[n * 4 + 0];
    const int qi = pos[n * 4 + 1];
    const int qj = pos[n * 4 + 2];
    const int ql = pos[n * 4 + 3];

    // q RoPE -> qs (threads 0..191)
    if (tid < NHEAD * HALFD) {
        int h = tid / HALFD, d = tid - (tid / HALFD) * HALFD;
        float2 cs = (d < 8) ? tabS[qi * 8 + d]
                  : (d < 16) ? tabS[qj * 8 + (d - 8)]
                             : tabL[ql * 8 + (d - 16)];
        float x1 = qproj[(size_t)n * DIM + h * HDIM + d];
        float x2 = qproj[(size_t)n * DIM + h * HDIM + HALFD + d];
        qs[h * HDIM + d]         = x1 * cs.x - x2 * cs.y;
        qs[h * HDIM + HALFD + d] = x1 * cs.y + x2 * cs.x;
    }

    // per-key geometry, pure integer: center = floor((q+0.5)*2^(ql-l))
    if (tid < NKEY) {
        int kk = tid;
        int l = kk / 49, rem = kk - l * 49;
        int a = rem / 7, bb2 = rem - a * 7;
        int Hl = 64 >> l;
        int off = (l == 0) ? 0 : (l == 1) ? 4096 : (l == 2) ? 5120 : 5376;
        int e = ql - l;
        int ti = 2 * qi + 1, tj = 2 * qj + 1;
        int ci = (e >= 1) ? (ti << (e - 1)) : (ti >> (1 - e));
        int cj = (e >= 1) ? (tj << (e - 1)) : (tj >> (1 - e));
        int ii = ci + a - 3, jj = cj + bb2 - 3;
        int valid = (ii >= 0) && (ii < Hl) && (jj >= 0) && (jj < Hl);
        ii = min(max(ii, 0), Hl - 1); jj = min(max(jj, 0), Hl - 1);
        flatL[kk]  = off + ii * Hl + jj;
        validL[kk] = valid;
    }
    __syncthreads();

    const size_t bbase = (size_t)b * TOTAL;

    // scores: 8 heads x 196 keys
    for (int idx = tid; idx < NHEAD * NKEY; idx += 256) {
        int h = idx / NKEY, kk = idx - h * NKEY;
        const bf16_t* krow = kvm + (bbase + (size_t)flatL[kk]) * (2 * DIM) + h * HDIM;
        bf16x8 kv[6];
#pragma unroll
        for (int i = 0; i < 6; ++i) kv[i] = *(const bf16x8*)(krow + i * 8);
        float dot = 0.f;
#pragma unroll
        for (int i = 0; i < 6; ++i)
#pragma unroll
            for (int e = 0; e < 8; ++e)
                dot += (float)kv[i][e] * qs[h * HDIM + i * 8 + e];
        float score = dot * 0.14433756729740643f;  // 1/sqrt(48)
        if (!validL[kk]) score = -1e9f;
        sc[h * NKEY + kk] = score;
    }
    __syncthreads();

    // softmax: head h handled by threads [h*32, h*32+32)
    {
        int h = tid >> 5, lg = tid & 31;
        float mx = -1e30f;
        for (int j = lg; j < NKEY; j += 32) mx = fmaxf(mx, sc[h * NKEY + j]);
#pragma unroll
        for (int m = 16; m; m >>= 1) mx = fmaxf(mx, __shfl_xor(mx, m));
        float sum = 0.f;
        for (int j = lg; j < NKEY; j += 32) {
            float e = __expf(sc[h * NKEY + j] - mx);
            sc[h * NKEY + j] = e; sum += e;
        }
#pragma unroll
        for (int m = 16; m; m >>= 1) sum += __shfl_xor(sum, m);
        float inv = 1.f / sum;
        for (int j = lg; j < NKEY; j += 32) sc[h * NKEY + j] *= inv;
    }
    __syncthreads();

    // V accumulation: 192 threads x 2 dims, unroll 8 for miss overlap
    if (tid < 192) {
        int h = tid / 24;
        float a0 = 0.f, a1 = 0.f;
        const float* sch = sc + h * NKEY;
#pragma unroll 8
        for (int kk = 0; kk < NKEY; ++kk) {
            float w = sch[kk];
            const bf16_t* vr = kvm + (bbase + (size_t)flatL[kk]) * (2 * DIM) + DIM + 2 * tid;
            bf16x2 vv = *(const bf16x2*)vr;
            a0 += w * (float)vv[0];
            a1 += w * (float)vv[1];
        }
        bf16x2 o = { (bf16_t)a0, (bf16_t)a1 };
        *(bf16x2*)(attn_out + (size_t)n * DIM + 2 * tid) = o;
    }
}

// ---------------------------------------------------------------------------
extern "C" void kernel_launch(void* const* d_in, const int* in_sizes, int n_in,
                              void* d_out, int out_size, void* d_ws, size_t ws_size,
                              hipStream_t stream)
{
    const float* query  = (const float*)d_in[0];
    const int*   pos    = (const int*)d_in[1];
    const float* fmaps  = (const float*)d_in[3];
    const float* nw     = (const float*)d_in[5];
    const float* nb     = (const float*)d_in[6];
    const float* wq     = (const float*)d_in[7];
    const float* wkv    = (const float*)d_in[8];
    const float* wout   = (const float*)d_in[9];
    float* out = (float*)d_out;

    const int Mkv = in_sizes[3] / DIM;  // B*total = 21760

    char* w = (char*)d_ws;
    auto alloc = [&](size_t bytes) { char* p = w; w += (bytes + 255) & ~(size_t)255; return p; };
    bf16_t* x_ln    = (bf16_t*)alloc((size_t)NQ * DIM * 2);
    float*  qproj   = (float*) alloc((size_t)NQ * DIM * 4);
    bf16_t* attn_o  = (bf16_t*)alloc((size_t)NQ * DIM * 2);
    bf16_t* kvm     = (bf16_t*)alloc((size_t)Mkv * 2 * DIM * 2);
    bf16_t* wq_bf   = (bf16_t*)alloc((size_t)DIM * DIM * 2);
    bf16_t* wkv_bf  = (bf16_t*)alloc((size_t)2 * DIM * DIM * 2);
    bf16_t* wout_bf = (bf16_t*)alloc((size_t)DIM * DIM * 2);
    float2* tabS    = (float2*)alloc(512 * 8);
    float2* tabL    = (float2*)alloc(32 * 8);

    prep_kernel<<<577, 256, 0, stream>>>(
        wq, wkv, wout, wq_bf, wkv_bf, wout_bf, tabS, tabL);
    ln_kernel<<<NQ, 64, 0, stream>>>(query, nw, nb, x_ln);
    gemm_bf16<0, 64, 0><<<dim3(DIM / 64, NQ / 64), 256, 0, stream>>>(
        x_ln, wq_bf, (void*)qproj, nullptr, NQ, DIM, DIM);
    gemm_bf16<2, 128, 1><<<dim3((2 * DIM) / 128, Mkv / 128), 256, 0, stream>>>(
        fmaps, wkv_bf, (void*)kvm, nullptr, Mkv, 2 * DIM, DIM);
    rope_k_kernel<<<(Mkv * NHEAD + 255) / 256, 256, 0, stream>>>(kvm, tabS, tabL, Mkv);
    attn_kernel<<<NQ, 256, 0, stream>>>(qproj, pos, kvm, tabS, tabL, attn_o);
    gemm_bf16<1, 64, 0><<<dim3(DIM / 64, NQ / 64), 256, 0, stream>>>(
        attn_o, wout_bf, (void*)out, query, NQ, DIM, DIM);
}

// Round 12
// 105.029 us; speedup vs baseline: 1.1574x; 1.1574x over previous
//
#include <hip/hip_runtime.h>
#include <hip/hip_bf16.h>

typedef __bf16 bf16_t;
typedef __attribute__((ext_vector_type(4))) float f32x4;
typedef __attribute__((ext_vector_type(8))) __bf16 bf16x8;
typedef __attribute__((ext_vector_type(4))) __bf16 bf16x4;
typedef __attribute__((ext_vector_type(2))) __bf16 bf16x2;

#define NQ    1024
#define DIM   384
#define NHEAD 8
#define HDIM  48
#define HALFD 24
#define NKEY  196
#define TOTAL 5440   // 64*64 + 32*32 + 16*16 + 8*8

typedef __attribute__((address_space(1))) void gas_void;
typedef __attribute__((address_space(3))) void las_void;
__device__ __forceinline__ void gload16(const void* g, void* l) {
    __builtin_amdgcn_global_load_lds((gas_void*)g, (las_void*)l, 16, 0, 0);
}

// ---------------------------------------------------------------------------
// prep: fmaps fp32->bf16 (blocks [0,nfm)), weights (nfm..nfm+575),
// sincos tables (block nfm+576).
// ---------------------------------------------------------------------------
__global__ __launch_bounds__(256) void prep_kernel(
    const float* __restrict__ fmaps, bf16_t* __restrict__ fm_bf, int nfm,
    const float* __restrict__ wq, const float* __restrict__ wkv,
    const float* __restrict__ wout, bf16_t* __restrict__ wq_bf,
    bf16_t* __restrict__ wkv_bf, bf16_t* __restrict__ wout_bf,
    float2* __restrict__ tabS, float2* __restrict__ tabL)
{
    int bid = blockIdx.x;
    if (bid < nfm) {
        int i = bid * 256 + threadIdx.x;
        float4 v = ((const float4*)fmaps)[i];
        bf16x4 o = { (bf16_t)v.x, (bf16_t)v.y, (bf16_t)v.z, (bf16_t)v.w };
        ((bf16x4*)fm_bf)[i] = o;
        return;
    }
    int wb = bid - nfm;
    if (wb == 576) {
        int t = threadIdx.x;
        if (t < 512) {
            int i = t >> 3, f = t & 7;
            float fr = powf(10.f, -(float)f / 8.f);
            float s, c; sincosf((float)i * fr, &s, &c);
            tabS[t] = make_float2(c, s);
        } else if (t < 544) {
            int u = t - 512; int l = u >> 3, f = u & 7;
            float fr = powf(10.f, (float)f / 8.f);
            float s, c; sincosf((float)l * fr, &s, &c);
            tabL[u] = make_float2(c, s);
        }
        return;
    }
    int i = wb * 256 + threadIdx.x;
    const float* src; bf16_t* dst; int off;
    if (i < 36864)       { src = wq;   dst = wq_bf;   off = i; }
    else if (i < 110592) { src = wkv;  dst = wkv_bf;  off = i - 36864; }
    else                 { src = wout; dst = wout_bf; off = i - 110592; }
    float4 v = ((const float4*)src)[off];
    bf16x4 o = { (bf16_t)v.x, (bf16_t)v.y, (bf16_t)v.z, (bf16_t)v.w };
    ((bf16x4*)dst)[off] = o;
}

// ---------------------------------------------------------------------------
// bf16 NT GEMM (global_load_lds + swizzle, XCD block swizzle) — R7-proven.
// EPI: 0 = fp32 C, 1 = fp32 C + resid, 2 = bf16 C.  BT = 128 or 64.
// ---------------------------------------------------------------------------
template<int EPI, int BT>
__global__ __launch_bounds__(256) void gemm_bf16(
    const bf16_t* __restrict__ A, const bf16_t* __restrict__ Bw,
    void* __restrict__ Cp, const float* __restrict__ resid,
    int M, int Nout, int K)
{
    constexpr int FRG = BT / 32;
    constexpr int WT  = BT / 2;
    __shared__ bf16_t As[BT * 64];
    __shared__ bf16_t Bs[BT * 64];
    const int tid = threadIdx.x;

    const int bid = blockIdx.y * gridDim.x + blockIdx.x;
    const int nwg = gridDim.x * gridDim.y;
    const int qq = nwg >> 3, rr8 = nwg & 7;
    const int xcd = bid & 7, loc = bid >> 3;
    const int swz = (xcd < rr8 ? xcd * (qq + 1) : rr8 * (qq + 1) + (xcd - rr8) * qq) + loc;
    const int bm = swz / gridDim.x, bn = swz % gridDim.x;

    const int wave = tid >> 6, lane = tid & 63;
    const int wr   = wave >> 1, wc = wave & 1;
    const int fr   = lane & 15, g = lane >> 4;

    f32x4 acc[FRG][FRG];
#pragma unroll
    for (int i = 0; i < FRG; ++i)
#pragma unroll
        for (int j = 0; j < FRG; ++j) acc[i][j] = (f32x4){0.f, 0.f, 0.f, 0.f};

    const bf16_t* Ab = A  + (size_t)bm * BT * K;
    const bf16_t* Bb = Bw + (size_t)bn * BT * K;

    for (int kt = 0; kt < K; kt += 64) {
        __syncthreads();
#pragma unroll
        for (int it = 0; it < BT / 32; ++it) {
            int chunk = it * 256 + tid;
            int row = chunk >> 3, c8 = chunk & 7;
            int sc8 = c8 ^ (row & 7);
            gload16(Ab + (size_t)row * K + kt + sc8 * 8, As + chunk * 8);
            gload16(Bb + (size_t)row * K + kt + sc8 * 8, Bs + chunk * 8);
        }
        __syncthreads();
#pragma unroll
        for (int kk = 0; kk < 2; ++kk) {
            bf16x8 af[FRG], bfr[FRG];
#pragma unroll
            for (int mi = 0; mi < FRG; ++mi) {
                int row = wr * WT + mi * 16 + fr;
                int c = (kk * 4 + g) ^ (row & 7);
                af[mi] = *(const bf16x8*)(As + row * 64 + c * 8);
            }
#pragma unroll
            for (int ni = 0; ni < FRG; ++ni) {
                int row = wc * WT + ni * 16 + fr;
                int c = (kk * 4 + g) ^ (row & 7);
                bfr[ni] = *(const bf16x8*)(Bs + row * 64 + c * 8);
            }
#pragma unroll
            for (int mi = 0; mi < FRG; ++mi)
#pragma unroll
                for (int ni = 0; ni < FRG; ++ni)
                    acc[mi][ni] = __builtin_amdgcn_mfma_f32_16x16x32_bf16(
                        af[mi], bfr[ni], acc[mi][ni], 0, 0, 0);
        }
    }

    const int r0 = g << 2;
#pragma unroll
    for (int mi = 0; mi < FRG; ++mi) {
#pragma unroll
        for (int ni = 0; ni < FRG; ++ni) {
#pragma unroll
            for (int e = 0; e < 4; ++e) {
                int row = bm * BT + wr * WT + mi * 16 + r0 + e;
                int col = bn * BT + wc * WT + ni * 16 + fr;
                float v = acc[mi][ni][e];
                if (EPI == 2) {
                    ((bf16_t*)Cp)[(size_t)row * Nout + col] = (bf16_t)v;
                } else {
                    if (EPI == 1) v += resid[(size_t)row * Nout + col];
                    ((float*)Cp)[(size_t)row * Nout + col] = v;
                }
            }
        }
    }
}

// ---------------------------------------------------------------------------
__global__ __launch_bounds__(64) void ln_kernel(
    const float* __restrict__ q, const float* __restrict__ w,
    const float* __restrict__ b, bf16_t* __restrict__ xout)
{
    const int n = blockIdx.x, lane = threadIdx.x;
    const float* row = q + (size_t)n * DIM;
    float v[6], s = 0.f, s2 = 0.f;
#pragma unroll
    for (int i = 0; i < 6; ++i) {
        v[i] = row[lane + i * 64];
        s += v[i]; s2 += v[i] * v[i];
    }
#pragma unroll
    for (int m = 32; m; m >>= 1) { s += __shfl_xor(s, m); s2 += __shfl_xor(s2, m); }
    float mu  = s * (1.f / DIM);
    float var = s2 * (1.f / DIM) - mu * mu;
    float rs  = rsqrtf(var + 1e-5f);
#pragma unroll
    for (int i = 0; i < 6; ++i) {
        int d = lane + i * 64;
        xout[(size_t)n * DIM + d] = (bf16_t)((v[i] - mu) * rs * w[d] + b[d]);
    }
}

// ---------------------------------------------------------------------------
// Pre-rotate the k-half of the kv map in place. One thread per (row, head).
// ---------------------------------------------------------------------------
__global__ __launch_bounds__(256) void rope_k_kernel(
    bf16_t* __restrict__ kvm, const float2* __restrict__ tabS,
    const float2* __restrict__ tabL, int Mkv)
{
    int t = blockIdx.x * 256 + threadIdx.x;
    if (t >= Mkv * NHEAD) return;
    int row = t >> 3, h = t & 7;

    int rr = row % TOTAL;
    int l, i, j;
    if (rr < 4096)      { l = 0; i = rr >> 6;               j = rr & 63; }
    else if (rr < 5120) { l = 1; int u = rr - 4096; i = u >> 5; j = u & 31; }
    else if (rr < 5376) { l = 2; int u = rr - 5120; i = u >> 4; j = u & 15; }
    else                { l = 3; int u = rr - 5376; i = u >> 3; j = u & 7;  }

    bf16_t* base = kvm + (size_t)row * (2 * DIM) + h * HDIM;
    bf16x8 xa[3], xb[3];
#pragma unroll
    for (int k = 0; k < 3; ++k) {
        xa[k] = *(const bf16x8*)(base + 8 * k);
        xb[k] = *(const bf16x8*)(base + HALFD + 8 * k);
    }
#pragma unroll
    for (int d = 0; d < HALFD; ++d) {
        float2 cs = (d < 8) ? tabS[i * 8 + d]
                  : (d < 16) ? tabS[j * 8 + (d - 8)]
                             : tabL[l * 8 + (d - 16)];
        float x1 = (float)xa[d >> 3][d & 7];
        float x2 = (float)xb[d >> 3][d & 7];
        xa[d >> 3][d & 7] = (bf16_t)(x1 * cs.x - x2 * cs.y);
        xb[d >> 3][d & 7] = (bf16_t)(x1 * cs.y + x2 * cs.x);
    }
#pragma unroll
    for (int k = 0; k < 3; ++k) {
        *(bf16x8*)(base + 8 * k)         = xa[k];
        *(bf16x8*)(base + HALFD + 8 * k) = xb[k];
    }
}

// ---------------------------------------------------------------------------
// Attention: TWO blocks (256 threads) per query — heads 0-3 / 4-7.
// grid 2048 => 8 blocks/CU (vs 4). bid&7 = XCD unchanged: both halves of a
// query and its whole 128-query chunk stay on one XCD's L2 slice.
// ---------------------------------------------------------------------------
__global__ __launch_bounds__(256) void attn_kernel(
    const float* __restrict__ qproj,   // (N,384) pre-RoPE fp32
    const int*   __restrict__ pos,     // (N,4) b,i,j,l
    const bf16_t* __restrict__ kvm,    // (B*total, 768) bf16, k pre-rotated
    const float2* __restrict__ tabS, const float2* __restrict__ tabL,
    bf16_t* __restrict__ attn_out)     // (N,384) bf16
{
    __shared__ float qs[4 * HDIM];
    __shared__ float sc[4 * NKEY];
    __shared__ int   flatL[NKEY], validL[NKEY];
    __shared__ float ptv[4][2][HALFD][2];

    const int bid = blockIdx.x, tid = threadIdx.x;
    const int n    = ((bid & 7) << 7) | (bid >> 4);   // XCD-chunked remap
    const int h0   = ((bid >> 3) & 1) * 4;            // head half
    const int b  = pos[n * 4 + 0];
    const int qi = pos[n * 4 + 1];
    const int qj = pos[n * 4 + 2];
    const int ql = pos[n * 4 + 3];

    // per-key geometry (tid<196), pure integer
    if (tid < NKEY) {
        int kk = tid;
        int l = kk / 49, rem = kk - l * 49;
        int a = rem / 7, bb2 = rem - a * 7;
        int Hl = 64 >> l;
        int off = (l == 0) ? 0 : (l == 1) ? 4096 : (l == 2) ? 5120 : 5376;
        int e = ql - l;
        int ti = 2 * qi + 1, tj = 2 * qj + 1;
        int ci = (e >= 1) ? (ti << (e - 1)) : (ti >> (1 - e));
        int cj = (e >= 1) ? (tj << (e - 1)) : (tj >> (1 - e));
        int ii = ci + a - 3, jj = cj + bb2 - 3;
        int valid = (ii >= 0) && (ii < Hl) && (jj >= 0) && (jj < Hl);
        ii = min(max(ii, 0), Hl - 1); jj = min(max(jj, 0), Hl - 1);
        flatL[kk]  = off + ii * Hl + jj;
        validL[kk] = valid;
    }
    // q RoPE for this block's 4 heads (tid<96)
    if (tid < 4 * HALFD) {
        int hh = tid / HALFD, d = tid - hh * HALFD;
        int h = h0 + hh;
        float2 cs = (d < 8) ? tabS[qi * 8 + d]
                  : (d < 16) ? tabS[qj * 8 + (d - 8)]
                             : tabL[ql * 8 + (d - 16)];
        float x1 = qproj[(size_t)n * DIM + h * HDIM + d];
        float x2 = qproj[(size_t)n * DIM + h * HDIM + HALFD + d];
        qs[hh * HDIM + d]         = x1 * cs.x - x2 * cs.y;
        qs[hh * HDIM + HALFD + d] = x1 * cs.y + x2 * cs.x;
    }
    __syncthreads();

    const size_t bbase = (size_t)b * TOTAL;

    // scores: 4 heads x 196 keys
    for (int idx = tid; idx < 4 * NKEY; idx += 256) {
        int hh = idx / NKEY, kk = idx - hh * NKEY;
        const bf16_t* krow = kvm + (bbase + (size_t)flatL[kk]) * (2 * DIM) + (h0 + hh) * HDIM;
        bf16x8 kv[6];
#pragma unroll
        for (int i = 0; i < 6; ++i) kv[i] = *(const bf16x8*)(krow + i * 8);
        float dot = 0.f;
#pragma unroll
        for (int i = 0; i < 6; ++i)
#pragma unroll
            for (int e = 0; e < 8; ++e)
                dot += (float)kv[i][e] * qs[hh * HDIM + i * 8 + e];
        float score = dot * 0.14433756729740643f;  // 1/sqrt(48)
        if (!validL[kk]) score = -1e9f;
        sc[hh * NKEY + kk] = score;
    }
    __syncthreads();

    // softmax: wave w handles head hh=w (64-lane shuffle reduce)
    {
        int wv = tid >> 6, lane = tid & 63;
        float* sch = sc + wv * NKEY;
        float mx = -1e30f;
        for (int j2 = lane; j2 < NKEY; j2 += 64) mx = fmaxf(mx, sch[j2]);
#pragma unroll
        for (int o = 32; o; o >>= 1) mx = fmaxf(mx, __shfl_xor(mx, o));
        float sum = 0.f;
        for (int j2 = lane; j2 < NKEY; j2 += 64) {
            float e = __expf(sch[j2] - mx);
            sch[j2] = e; sum += e;
        }
#pragma unroll
        for (int o = 32; o; o >>= 1) sum += __shfl_xor(sum, o);
        float inv = 1.f / sum;
        for (int j2 = lane; j2 < NKEY; j2 += 64) sch[j2] *= inv;
    }
    __syncthreads();

    // V accumulation: 192 threads = 4 heads x 24 dim-pairs x 2 key-groups
    if (tid < 192) {
        int hh = tid / 48, rem = tid - hh * 48;
        int g2 = rem / HALFD, pr = rem - g2 * HALFD;
        float a0 = 0.f, a1 = 0.f;
        const float* sch = sc + hh * NKEY;
#pragma unroll 4
        for (int kk = g2; kk < NKEY; kk += 2) {
            float w = sch[kk];
            bf16x2 vv = *(const bf16x2*)(kvm + (bbase + (size_t)flatL[kk]) * (2 * DIM)
                                         + DIM + (h0 + hh) * HDIM + 2 * pr);
            a0 += w * (float)vv[0];
            a1 += w * (float)vv[1];
        }
        ptv[hh][g2][pr][0] = a0; ptv[hh][g2][pr][1] = a1;
    }
    __syncthreads();
    if (tid < 96) {
        int hh = tid / HALFD, pr = tid - hh * HALFD;
        float s0 = ptv[hh][0][pr][0] + ptv[hh][1][pr][0];
        float s1 = ptv[hh][0][pr][1] + ptv[hh][1][pr][1];
        bf16x2 o = { (bf16_t)s0, (bf16_t)s1 };
        *(bf16x2*)(attn_out + (size_t)n * DIM + (h0 + hh) * HDIM + 2 * pr) = o;
    }
}

// ---------------------------------------------------------------------------
extern "C" void kernel_launch(void* const* d_in, const int* in_sizes, int n_in,
                              void* d_out, int out_size, void* d_ws, size_t ws_size,
                              hipStream_t stream)
{
    const float* query  = (const float*)d_in[0];
    const int*   pos    = (const int*)d_in[1];
    const float* fmaps  = (const float*)d_in[3];
    const float* nw     = (const float*)d_in[5];
    const float* nb     = (const float*)d_in[6];
    const float* wq     = (const float*)d_in[7];
    const float* wkv    = (const float*)d_in[8];
    const float* wout   = (const float*)d_in[9];
    float* out = (float*)d_out;

    const int Mkv = in_sizes[3] / DIM;  // B*total = 21760

    char* w = (char*)d_ws;
    auto alloc = [&](size_t bytes) { char* p = w; w += (bytes + 255) & ~(size_t)255; return p; };
    bf16_t* x_ln    = (bf16_t*)alloc((size_t)NQ * DIM * 2);
    float*  qproj   = (float*) alloc((size_t)NQ * DIM * 4);
    bf16_t* attn_o  = (bf16_t*)alloc((size_t)NQ * DIM * 2);
    bf16_t* kvm     = (bf16_t*)alloc((size_t)Mkv * 2 * DIM * 2);
    bf16_t* fm_bf   = (bf16_t*)alloc((size_t)Mkv * DIM * 2);
    bf16_t* wq_bf   = (bf16_t*)alloc((size_t)DIM * DIM * 2);
    bf16_t* wkv_bf  = (bf16_t*)alloc((size_t)2 * DIM * DIM * 2);
    bf16_t* wout_bf = (bf16_t*)alloc((size_t)DIM * DIM * 2);
    float2* tabS    = (float2*)alloc(512 * 8);
    float2* tabL    = (float2*)alloc(32 * 8);

    const int nfm = Mkv * DIM / 4 / 256;   // fmaps cvt blocks (8160)
    prep_kernel<<<nfm + 577, 256, 0, stream>>>(
        fmaps, fm_bf, nfm, wq, wkv, wout, wq_bf, wkv_bf, wout_bf, tabS, tabL);
    ln_kernel<<<NQ, 64, 0, stream>>>(query, nw, nb, x_ln);
    gemm_bf16<0, 64><<<dim3(DIM / 64, NQ / 64), 256, 0, stream>>>(
        x_ln, wq_bf, (void*)qproj, nullptr, NQ, DIM, DIM);
    gemm_bf16<2, 128><<<dim3((2 * DIM) / 128, Mkv / 128), 256, 0, stream>>>(
        fm_bf, wkv_bf, (void*)kvm, nullptr, Mkv, 2 * DIM, DIM);
    rope_k_kernel<<<(Mkv * NHEAD + 255) / 256, 256, 0, stream>>>(kvm, tabS, tabL, Mkv);
    attn_kernel<<<2 * NQ, 256, 0, stream>>>(qproj, pos, kvm, tabS, tabL, attn_o);
    gemm_bf16<1, 64><<<dim3(DIM / 64, NQ / 64), 256, 0, stream>>>(
        attn_o, wout_bf, (void*)out, query, NQ, DIM, DIM);
}

// Round 13
// 93.113 us; speedup vs baseline: 1.3055x; 1.1280x over previous
//
#include <hip/hip_runtime.h>
#include <hip/hip_bf16.h>

typedef __bf16 bf16_t;
typedef __attribute__((ext_vector_type(4))) float f32x4;
typedef __attribute__((ext_vector_type(8))) __bf16 bf16x8;
typedef __attribute__((ext_vector_type(4))) __bf16 bf16x4;
typedef __attribute__((ext_vector_type(2))) __bf16 bf16x2;

#define NQ    1024
#define DIM   384
#define NHEAD 8
#define HDIM  48
#define HALFD 24
#define NKEY  196
#define TOTAL 5440   // 64*64 + 32*32 + 16*16 + 8*8

typedef __attribute__((address_space(1))) void gas_void;
typedef __attribute__((address_space(3))) void las_void;
__device__ __forceinline__ void gload16(const void* g, void* l) {
    __builtin_amdgcn_global_load_lds((gas_void*)g, (las_void*)l, 16, 0, 0);
}

// ---------------------------------------------------------------------------
// prep: fmaps fp32->bf16 (blocks [0,nfm)), weights (nfm..nfm+575),
// sincos tables (block nfm+576).
// ---------------------------------------------------------------------------
__global__ __launch_bounds__(256) void prep_kernel(
    const float* __restrict__ fmaps, bf16_t* __restrict__ fm_bf, int nfm,
    const float* __restrict__ wq, const float* __restrict__ wkv,
    const float* __restrict__ wout, bf16_t* __restrict__ wq_bf,
    bf16_t* __restrict__ wkv_bf, bf16_t* __restrict__ wout_bf,
    float2* __restrict__ tabS, float2* __restrict__ tabL)
{
    int bid = blockIdx.x;
    if (bid < nfm) {
        int i = bid * 256 + threadIdx.x;
        float4 v = ((const float4*)fmaps)[i];
        bf16x4 o = { (bf16_t)v.x, (bf16_t)v.y, (bf16_t)v.z, (bf16_t)v.w };
        ((bf16x4*)fm_bf)[i] = o;
        return;
    }
    int wb = bid - nfm;
    if (wb == 576) {
        int t = threadIdx.x;
        if (t < 512) {
            int i = t >> 3, f = t & 7;
            float fr = powf(10.f, -(float)f / 8.f);
            float s, c; sincosf((float)i * fr, &s, &c);
            tabS[t] = make_float2(c, s);
        } else if (t < 544) {
            int u = t - 512; int l = u >> 3, f = u & 7;
            float fr = powf(10.f, (float)f / 8.f);
            float s, c; sincosf((float)l * fr, &s, &c);
            tabL[u] = make_float2(c, s);
        }
        return;
    }
    int i = wb * 256 + threadIdx.x;
    const float* src; bf16_t* dst; int off;
    if (i < 36864)       { src = wq;   dst = wq_bf;   off = i; }
    else if (i < 110592) { src = wkv;  dst = wkv_bf;  off = i - 36864; }
    else                 { src = wout; dst = wout_bf; off = i - 110592; }
    float4 v = ((const float4*)src)[off];
    bf16x4 o = { (bf16_t)v.x, (bf16_t)v.y, (bf16_t)v.z, (bf16_t)v.w };
    ((bf16x4*)dst)[off] = o;
}

// ---------------------------------------------------------------------------
// bf16 NT GEMM (global_load_lds + swizzle, XCD block swizzle) — R7-proven.
// EPI: 0 = fp32 C, 1 = fp32 C + resid, 2 = bf16 C.  BT = 128 or 64.
// ---------------------------------------------------------------------------
template<int EPI, int BT>
__global__ __launch_bounds__(256) void gemm_bf16(
    const bf16_t* __restrict__ A, const bf16_t* __restrict__ Bw,
    void* __restrict__ Cp, const float* __restrict__ resid,
    int M, int Nout, int K)
{
    constexpr int FRG = BT / 32;
    constexpr int WT  = BT / 2;
    __shared__ bf16_t As[BT * 64];
    __shared__ bf16_t Bs[BT * 64];
    const int tid = threadIdx.x;

    const int bid = blockIdx.y * gridDim.x + blockIdx.x;
    const int nwg = gridDim.x * gridDim.y;
    const int qq = nwg >> 3, rr8 = nwg & 7;
    const int xcd = bid & 7, loc = bid >> 3;
    const int swz = (xcd < rr8 ? xcd * (qq + 1) : rr8 * (qq + 1) + (xcd - rr8) * qq) + loc;
    const int bm = swz / gridDim.x, bn = swz % gridDim.x;

    const int wave = tid >> 6, lane = tid & 63;
    const int wr   = wave >> 1, wc = wave & 1;
    const int fr   = lane & 15, g = lane >> 4;

    f32x4 acc[FRG][FRG];
#pragma unroll
    for (int i = 0; i < FRG; ++i)
#pragma unroll
        for (int j = 0; j < FRG; ++j) acc[i][j] = (f32x4){0.f, 0.f, 0.f, 0.f};

    const bf16_t* Ab = A  + (size_t)bm * BT * K;
    const bf16_t* Bb = Bw + (size_t)bn * BT * K;

    for (int kt = 0; kt < K; kt += 64) {
        __syncthreads();
#pragma unroll
        for (int it = 0; it < BT / 32; ++it) {
            int chunk = it * 256 + tid;
            int row = chunk >> 3, c8 = chunk & 7;
            int sc8 = c8 ^ (row & 7);
            gload16(Ab + (size_t)row * K + kt + sc8 * 8, As + chunk * 8);
            gload16(Bb + (size_t)row * K + kt + sc8 * 8, Bs + chunk * 8);
        }
        __syncthreads();
#pragma unroll
        for (int kk = 0; kk < 2; ++kk) {
            bf16x8 af[FRG], bfr[FRG];
#pragma unroll
            for (int mi = 0; mi < FRG; ++mi) {
                int row = wr * WT + mi * 16 + fr;
                int c = (kk * 4 + g) ^ (row & 7);
                af[mi] = *(const bf16x8*)(As + row * 64 + c * 8);
            }
#pragma unroll
            for (int ni = 0; ni < FRG; ++ni) {
                int row = wc * WT + ni * 16 + fr;
                int c = (kk * 4 + g) ^ (row & 7);
                bfr[ni] = *(const bf16x8*)(Bs + row * 64 + c * 8);
            }
#pragma unroll
            for (int mi = 0; mi < FRG; ++mi)
#pragma unroll
                for (int ni = 0; ni < FRG; ++ni)
                    acc[mi][ni] = __builtin_amdgcn_mfma_f32_16x16x32_bf16(
                        af[mi], bfr[ni], acc[mi][ni], 0, 0, 0);
        }
    }

    const int r0 = g << 2;
#pragma unroll
    for (int mi = 0; mi < FRG; ++mi) {
#pragma unroll
        for (int ni = 0; ni < FRG; ++ni) {
#pragma unroll
            for (int e = 0; e < 4; ++e) {
                int row = bm * BT + wr * WT + mi * 16 + r0 + e;
                int col = bn * BT + wc * WT + ni * 16 + fr;
                float v = acc[mi][ni][e];
                if (EPI == 2) {
                    ((bf16_t*)Cp)[(size_t)row * Nout + col] = (bf16_t)v;
                } else {
                    if (EPI == 1) v += resid[(size_t)row * Nout + col];
                    ((float*)Cp)[(size_t)row * Nout + col] = v;
                }
            }
        }
    }
}

// ---------------------------------------------------------------------------
__global__ __launch_bounds__(64) void ln_kernel(
    const float* __restrict__ q, const float* __restrict__ w,
    const float* __restrict__ b, bf16_t* __restrict__ xout)
{
    const int n = blockIdx.x, lane = threadIdx.x;
    const float* row = q + (size_t)n * DIM;
    float v[6], s = 0.f, s2 = 0.f;
#pragma unroll
    for (int i = 0; i < 6; ++i) {
        v[i] = row[lane + i * 64];
        s += v[i]; s2 += v[i] * v[i];
    }
#pragma unroll
    for (int m = 32; m; m >>= 1) { s += __shfl_xor(s, m); s2 += __shfl_xor(s2, m); }
    float mu  = s * (1.f / DIM);
    float var = s2 * (1.f / DIM) - mu * mu;
    float rs  = rsqrtf(var + 1e-5f);
#pragma unroll
    for (int i = 0; i < 6; ++i) {
        int d = lane + i * 64;
        xout[(size_t)n * DIM + d] = (bf16_t)((v[i] - mu) * rs * w[d] + b[d]);
    }
}

// ---------------------------------------------------------------------------
// Pre-rotate the k-half of the kv map in place. One thread per (row, head).
// ---------------------------------------------------------------------------
__global__ __launch_bounds__(256) void rope_k_kernel(
    bf16_t* __restrict__ kvm, const float2* __restrict__ tabS,
    const float2* __restrict__ tabL, int Mkv)
{
    int t = blockIdx.x * 256 + threadIdx.x;
    if (t >= Mkv * NHEAD) return;
    int row = t >> 3, h = t & 7;

    int rr = row % TOTAL;
    int l, i, j;
    if (rr < 4096)      { l = 0; i = rr >> 6;               j = rr & 63; }
    else if (rr < 5120) { l = 1; int u = rr - 4096; i = u >> 5; j = u & 31; }
    else if (rr < 5376) { l = 2; int u = rr - 5120; i = u >> 4; j = u & 15; }
    else                { l = 3; int u = rr - 5376; i = u >> 3; j = u & 7;  }

    bf16_t* base = kvm + (size_t)row * (2 * DIM) + h * HDIM;
    bf16x8 xa[3], xb[3];
#pragma unroll
    for (int k = 0; k < 3; ++k) {
        xa[k] = *(const bf16x8*)(base + 8 * k);
        xb[k] = *(const bf16x8*)(base + HALFD + 8 * k);
    }
#pragma unroll
    for (int d = 0; d < HALFD; ++d) {
        float2 cs = (d < 8) ? tabS[i * 8 + d]
                  : (d < 16) ? tabS[j * 8 + (d - 8)]
                             : tabL[l * 8 + (d - 16)];
        float x1 = (float)xa[d >> 3][d & 7];
        float x2 = (float)xb[d >> 3][d & 7];
        xa[d >> 3][d & 7] = (bf16_t)(x1 * cs.x - x2 * cs.y);
        xb[d >> 3][d & 7] = (bf16_t)(x1 * cs.y + x2 * cs.x);
    }
#pragma unroll
    for (int k = 0; k < 3; ++k) {
        *(bf16x8*)(base + 8 * k)         = xa[k];
        *(bf16x8*)(base + HALFD + 8 * k) = xb[k];
    }
}

// ---------------------------------------------------------------------------
// Attention: one block (256 threads) per query — R7 structure, new V phase.
// XCD-chunked query remap: XCD x serves queries [128x, 128x+128).
// V phase: 5 key-groups x 48 dim-octets, 16B bf16x8 loads (4x fewer loads,
// ~4x shorter dependency chain than the scalar bf16x2 loop).
// ---------------------------------------------------------------------------
__global__ __launch_bounds__(256) void attn_kernel(
    const float* __restrict__ qproj,   // (N,384) pre-RoPE fp32
    const int*   __restrict__ pos,     // (N,4) b,i,j,l
    const bf16_t* __restrict__ kvm,    // (B*total, 768) bf16, k pre-rotated
    const float2* __restrict__ tabS, const float2* __restrict__ tabL,
    bf16_t* __restrict__ attn_out)     // (N,384) bf16
{
    __shared__ float qs[DIM];
    __shared__ float sc[NHEAD * NKEY];
    __shared__ int   flatL[NKEY], validL[NKEY];
    __shared__ float ptv[5][DIM];

    const int bid = blockIdx.x, tid = threadIdx.x;
    const int n = ((bid & 7) << 7) | (bid >> 3);   // XCD-chunked remap
    const int b  = pos[n * 4 + 0];
    const int qi = pos[n * 4 + 1];
    const int qj = pos[n * 4 + 2];
    const int ql = pos[n * 4 + 3];

    // q RoPE -> qs (threads 0..191)
    if (tid < NHEAD * HALFD) {
        int h = tid / HALFD, d = tid - (tid / HALFD) * HALFD;
        float2 cs = (d < 8) ? tabS[qi * 8 + d]
                  : (d < 16) ? tabS[qj * 8 + (d - 8)]
                             : tabL[ql * 8 + (d - 16)];
        float x1 = qproj[(size_t)n * DIM + h * HDIM + d];
        float x2 = qproj[(size_t)n * DIM + h * HDIM + HALFD + d];
        qs[h * HDIM + d]         = x1 * cs.x - x2 * cs.y;
        qs[h * HDIM + HALFD + d] = x1 * cs.y + x2 * cs.x;
    }

    // per-key geometry, pure integer: center = floor((q+0.5)*2^(ql-l))
    if (tid < NKEY) {
        int kk = tid;
        int l = kk / 49, rem = kk - l * 49;
        int a = rem / 7, bb2 = rem - a * 7;
        int Hl = 64 >> l;
        int off = (l == 0) ? 0 : (l == 1) ? 4096 : (l == 2) ? 5120 : 5376;
        int e = ql - l;
        int ti = 2 * qi + 1, tj = 2 * qj + 1;
        int ci = (e >= 1) ? (ti << (e - 1)) : (ti >> (1 - e));
        int cj = (e >= 1) ? (tj << (e - 1)) : (tj >> (1 - e));
        int ii = ci + a - 3, jj = cj + bb2 - 3;
        int valid = (ii >= 0) && (ii < Hl) && (jj >= 0) && (jj < Hl);
        ii = min(max(ii, 0), Hl - 1); jj = min(max(jj, 0), Hl - 1);
        flatL[kk]  = off + ii * Hl + jj;
        validL[kk] = valid;
    }
    __syncthreads();

    const size_t bbase = (size_t)b * TOTAL;

    // scores: 8 heads x 196 keys
    for (int idx = tid; idx < NHEAD * NKEY; idx += 256) {
        int h = idx / NKEY, kk = idx - h * NKEY;
        const bf16_t* krow = kvm + (bbase + (size_t)flatL[kk]) * (2 * DIM) + h * HDIM;
        bf16x8 kv[6];
#pragma unroll
        for (int i = 0; i < 6; ++i) kv[i] = *(const bf16x8*)(krow + i * 8);
        float dot = 0.f;
#pragma unroll
        for (int i = 0; i < 6; ++i)
#pragma unroll
            for (int e = 0; e < 8; ++e)
                dot += (float)kv[i][e] * qs[h * HDIM + i * 8 + e];
        float score = dot * 0.14433756729740643f;  // 1/sqrt(48)
        if (!validL[kk]) score = -1e9f;
        sc[h * NKEY + kk] = score;
    }
    __syncthreads();

    // softmax: head h handled by threads [h*32, h*32+32)
    {
        int h = tid >> 5, lg = tid & 31;
        float mx = -1e30f;
        for (int j = lg; j < NKEY; j += 32) mx = fmaxf(mx, sc[h * NKEY + j]);
#pragma unroll
        for (int m = 16; m; m >>= 1) mx = fmaxf(mx, __shfl_xor(mx, m));
        float sum = 0.f;
        for (int j = lg; j < NKEY; j += 32) {
            float e = __expf(sc[h * NKEY + j] - mx);
            sc[h * NKEY + j] = e; sum += e;
        }
#pragma unroll
        for (int m = 16; m; m >>= 1) sum += __shfl_xor(sum, m);
        float inv = 1.f / sum;
        for (int j = lg; j < NKEY; j += 32) sc[h * NKEY + j] *= inv;
    }
    __syncthreads();

    // V accumulation: 240 threads = 5 key-groups x 48 dim-octets (16B loads)
    if (tid < 240) {
        int g5 = tid / 48, o = tid - (tid / 48) * 48;  // key-group, dim-octet
        int h = o / 6;                                  // head of this octet
        float a[8];
#pragma unroll
        for (int e = 0; e < 8; ++e) a[e] = 0.f;
        const float* sch = sc + h * NKEY;
#pragma unroll 4
        for (int kk = g5; kk < NKEY; kk += 5) {
            float w = sch[kk];
            bf16x8 vv = *(const bf16x8*)(kvm + (bbase + (size_t)flatL[kk]) * (2 * DIM)
                                         + DIM + 8 * o);
#pragma unroll
            for (int e = 0; e < 8; ++e) a[e] += w * (float)vv[e];
        }
        float4 lo = { a[0], a[1], a[2], a[3] };
        float4 hi = { a[4], a[5], a[6], a[7] };
        *(float4*)(&ptv[g5][8 * o])     = lo;
        *(float4*)(&ptv[g5][8 * o + 4]) = hi;
    }
    __syncthreads();

    // final reduce over key-groups: 192 threads x 2 dims
    if (tid < 192) {
        int d0 = 2 * tid;
        float s0 = 0.f, s1 = 0.f;
#pragma unroll
        for (int g5 = 0; g5 < 5; ++g5) {
            s0 += ptv[g5][d0];
            s1 += ptv[g5][d0 + 1];
        }
        bf16x2 o = { (bf16_t)s0, (bf16_t)s1 };
        *(bf16x2*)(attn_out + (size_t)n * DIM + d0) = o;
    }
}

// ---------------------------------------------------------------------------
extern "C" void kernel_launch(void* const* d_in, const int* in_sizes, int n_in,
                              void* d_out, int out_size, void* d_ws, size_t ws_size,
                              hipStream_t stream)
{
    const float* query  = (const float*)d_in[0];
    const int*   pos    = (const int*)d_in[1];
    const float* fmaps  = (const float*)d_in[3];
    const float* nw     = (const float*)d_in[5];
    const float* nb     = (const float*)d_in[6];
    const float* wq     = (const float*)d_in[7];
    const float* wkv    = (const float*)d_in[8];
    const float* wout   = (const float*)d_in[9];
    float* out = (float*)d_out;

    const int Mkv = in_sizes[3] / DIM;  // B*total = 21760

    char* w = (char*)d_ws;
    auto alloc = [&](size_t bytes) { char* p = w; w += (bytes + 255) & ~(size_t)255; return p; };
    bf16_t* x_ln    = (bf16_t*)alloc((size_t)NQ * DIM * 2);
    float*  qproj   = (float*) alloc((size_t)NQ * DIM * 4);
    bf16_t* attn_o  = (bf16_t*)alloc((size_t)NQ * DIM * 2);
    bf16_t* kvm     = (bf16_t*)alloc((size_t)Mkv * 2 * DIM * 2);
    bf16_t* fm_bf   = (bf16_t*)alloc((size_t)Mkv * DIM * 2);
    bf16_t* wq_bf   = (bf16_t*)alloc((size_t)DIM * DIM * 2);
    bf16_t* wkv_bf  = (bf16_t*)alloc((size_t)2 * DIM * DIM * 2);
    bf16_t* wout_bf = (bf16_t*)alloc((size_t)DIM * DIM * 2);
    float2* tabS    = (float2*)alloc(512 * 8);
    float2* tabL    = (float2*)alloc(32 * 8);

    const int nfm = Mkv * DIM / 4 / 256;   // fmaps cvt blocks (8160)
    prep_kernel<<<nfm + 577, 256, 0, stream>>>(
        fmaps, fm_bf, nfm, wq, wkv, wout, wq_bf, wkv_bf, wout_bf, tabS, tabL);
    ln_kernel<<<NQ, 64, 0, stream>>>(query, nw, nb, x_ln);
    gemm_bf16<0, 64><<<dim3(DIM / 64, NQ / 64), 256, 0, stream>>>(
        x_ln, wq_bf, (void*)qproj, nullptr, NQ, DIM, DIM);
    gemm_bf16<2, 128><<<dim3((2 * DIM) / 128, Mkv / 128), 256, 0, stream>>>(
        fm_bf, wkv_bf, (void*)kvm, nullptr, Mkv, 2 * DIM, DIM);
    rope_k_kernel<<<(Mkv * NHEAD + 255) / 256, 256, 0, stream>>>(kvm, tabS, tabL, Mkv);
    attn_kernel<<<NQ, 256, 0, stream>>>(qproj, pos, kvm, tabS, tabL, attn_o);
    gemm_bf16<1, 64><<<dim3(DIM / 64, NQ / 64), 256, 0, stream>>>(
        attn_o, wout_bf, (void*)out, query, NQ, DIM, DIM);
}